// Round 7
// baseline (353.357 us; speedup 1.0000x reference)
//
#include <hip/hip_runtime.h>
#include <math.h>

// VQ-VAE vector quantizer for MI355X.
// z: [32, 64, 64, 64] fp32 (B, C=D, H, W), embedding: [1024, 64] fp32.
// Outputs (concatenated fp32 in d_out):
//   [0 .. 8388607]  quantized, layout (b, c, h, w)
//   [8388608]       loss = L + 0.25*L, L = mean((q - z)^2)
//   [8388609]       perplexity
//   [8388610 .. ]   encoding indices (as float), 131072 of them
//
// Round 7: MFMA filter + exact rescore.
//   s_exact[k] = ee[k] - 2*(z.e[k])  (zz is row-constant, ordering-irrelevant)
//   s~[k] via bf16 MFMA with z ~= zh + zl (RNE splits), e ~= eh:
//     |s~ - s_exact| <= 2*(2^-19 * sum|z_i|) + ~1.2e-5   (|e| < 2^-10)
//   Sweep 1: per-row min m~.  Sweep 2 (bit-identical arithmetic): collect
//   all k with s~ <= m~ + W_row,  W_row = 1e-5*sum|z_i| + 1e-4  (>=13x bound).
//   Rescore candidates with the reference-bit-exact fp32 chain
//   ((zz+ee) - 2*fma-chain-dot, (d,k)-lex min == first-occurrence argmin).
//   Candidate overflow (>16) -> exact full 1024-scan fallback.
// Fused epilogue: quantized gather/store (z already in LDS), fp64 loss,
// global count atomics. z read once, quantized written once.

#define NROWS 131072
#define KCODES 1024
#define DDIM 64
#define CAP 16

typedef __attribute__((ext_vector_type(8))) short short8v;  // 8 bf16
typedef __attribute__((ext_vector_type(4))) float f32x4;

// Prevent fp contraction (hipcc defaults to -ffp-contract=fast).
__device__ __forceinline__ float nofuse(float x) {
    asm("" : "+v"(x));
    return x;
}

// numpy pairwise_sum for n=64 of terms a[i]*a[i] (8-stripe + fixed tree).
template <typename F>
__device__ __forceinline__ float pairwise64_sq(F load) {
    float r[8];
#pragma unroll
    for (int j = 0; j < 8; j++) {
        float v = load(j);
        r[j] = nofuse(v * v);
    }
#pragma unroll
    for (int i = 8; i < 64; i += 8) {
#pragma unroll
        for (int j = 0; j < 8; j++) {
            float v = load(i + j);
            r[j] = r[j] + nofuse(v * v);
        }
    }
    return ((r[0] + r[1]) + (r[2] + r[3])) + ((r[4] + r[5]) + (r[6] + r[7]));
}

__device__ __forceinline__ unsigned short bf16_rne(float x) {
    unsigned u = __float_as_uint(x);
    u += 0x7FFFu + ((u >> 16) & 1u);
    return (unsigned short)(u >> 16);
}
__device__ __forceinline__ float bf16_tof(unsigned short h) {
    return __uint_as_float((unsigned)h << 16);
}

// --- kernel E: ee[k] (numpy-pairwise exact) + eh bf16 pack ---
__global__ __launch_bounds__(256) void kE(const float* __restrict__ emb,
                                          float* __restrict__ ee,
                                          unsigned short* __restrict__ eh_p) {
    int k = blockIdx.x * 256 + threadIdx.x;
    if (k >= KCODES) return;
    const float* er = emb + (size_t)k * DDIM;
    ee[k] = pairwise64_sq([&](int i) { return er[i]; });
#pragma unroll
    for (int i = 0; i < DDIM; i++) eh_p[(size_t)k * DDIM + i] = bf16_rne(er[i]);
}

#define MFMA_BF16(acc, a, b) \
    acc = __builtin_amdgcn_mfma_f32_16x16x32_bf16(a, b, acc, 0, 0, 0)

// --- kernel A2: MFMA filter + exact rescore + fused outputs ---
// Block: 256 threads (4 waves), 64 rows = one (b,h). Wave wv owns rows
// [wv*16, wv*16+16). MFMA 16x16x32 bf16:
//   A[m][k]: m = lane&15, k = (lane>>4)*8 + i  (short8v)
//   B[k][n]: n = lane&15, k = (lane>>4)*8 + i
//   D[m][n]: n = lane&15, m = (lane>>4)*4 + reg   (m89-verified)
__global__ __launch_bounds__(256) void kA2(const float* __restrict__ z,
                                           const float* __restrict__ emb,
                                           const float* __restrict__ ee,
                                           const unsigned short* __restrict__ eh_p,
                                           int* __restrict__ counts,
                                           float* __restrict__ out_idx,
                                           float* __restrict__ out_q,
                                           double* __restrict__ loss_sum) {
    __shared__ float zt[64][65];       // [w][d]
    __shared__ float zz_s[64];
    __shared__ float wq_s[64];         // per-row window W_row
    __shared__ int cnt_s[64];
    __shared__ unsigned short cand_s[64][CAP];
    __shared__ int idx_s[64];
    __shared__ double wred[4];

    const int tid = threadIdx.x;
    const int blk = blockIdx.x;        // 0..2047
    const int n0 = blk * 64;
    const int b = blk >> 6;
    const int h = blk & 63;

    // stage z tile (coalesced over w), transpose into LDS
    const float* zb = z + (size_t)b * 262144 + (size_t)h * 64;
    for (int i = tid; i < 64 * 64; i += 256) {
        int d = i >> 6, w = i & 63;
        zt[w][d] = zb[(size_t)d * 4096 + w];
    }
    __syncthreads();

    if (tid < 64) {
        const int w = tid;
        zz_s[w] = pairwise64_sq([&](int i) { return zt[w][i]; });
        float s = 0.0f;
#pragma unroll
        for (int i = 0; i < 64; i++) s += fabsf(zt[w][i]);
        wq_s[w] = fmaf(1e-5f, s, 1e-4f);
        cnt_s[w] = 0;
    }
    __syncthreads();

    const int wv = tid >> 6;           // wave id, owns rows wv*16..+15
    const int l = tid & 63;            // lane
    const int kg = (l >> 4) * 8;       // k-slice base within 32-wide tile

    // Build A fragments from LDS (zh = RNE bf16, zl = RNE bf16 residual)
    short8v ah[2], al[2];
    {
        const int arow = wv * 16 + (l & 15);
#pragma unroll
        for (int kt = 0; kt < 2; kt++) {
#pragma unroll
            for (int i = 0; i < 8; i++) {
                float x = zt[arow][kt * 32 + kg + i];
                unsigned short hh = bf16_rne(x);
                float r = x - bf16_tof(hh);
                ah[kt][i] = (short)hh;
                al[kt][i] = (short)bf16_rne(r);
            }
        }
    }

    // ---- sweep 1: per-row approx min ----
    float rm[4] = {INFINITY, INFINITY, INFINITY, INFINITY};
#pragma unroll 4
    for (int t = 0; t < 64; t++) {
        const int code = t * 16 + (l & 15);
        const unsigned short* eb = eh_p + (size_t)code * 64 + kg;
        short8v bh0 = *(const short8v*)eb;
        short8v bh1 = *(const short8v*)(eb + 32);
        f32x4 acc = {0.f, 0.f, 0.f, 0.f};
        MFMA_BF16(acc, ah[0], bh0);
        MFMA_BF16(acc, ah[1], bh1);
        MFMA_BF16(acc, al[0], bh0);
        MFMA_BF16(acc, al[1], bh1);
        const float eev = ee[code];
#pragma unroll
        for (int r = 0; r < 4; r++)
            rm[r] = fminf(rm[r], fmaf(-2.0f, acc[r], eev));
    }
    // reduce min across the 16 lanes sharing each row group
#pragma unroll
    for (int r = 0; r < 4; r++) {
        rm[r] = fminf(rm[r], __shfl_xor(rm[r], 1, 64));
        rm[r] = fminf(rm[r], __shfl_xor(rm[r], 2, 64));
        rm[r] = fminf(rm[r], __shfl_xor(rm[r], 4, 64));
        rm[r] = fminf(rm[r], __shfl_xor(rm[r], 8, 64));
    }
    float thr[4];
#pragma unroll
    for (int r = 0; r < 4; r++) {
        const int row = wv * 16 + ((l >> 4) << 2) + r;
        thr[r] = rm[r] + wq_s[row];
    }

    // ---- sweep 2: identical arithmetic, collect window candidates ----
#pragma unroll 4
    for (int t = 0; t < 64; t++) {
        const int code = t * 16 + (l & 15);
        const unsigned short* eb = eh_p + (size_t)code * 64 + kg;
        short8v bh0 = *(const short8v*)eb;
        short8v bh1 = *(const short8v*)(eb + 32);
        f32x4 acc = {0.f, 0.f, 0.f, 0.f};
        MFMA_BF16(acc, ah[0], bh0);
        MFMA_BF16(acc, ah[1], bh1);
        MFMA_BF16(acc, al[0], bh0);
        MFMA_BF16(acc, al[1], bh1);
        const float eev = ee[code];
#pragma unroll
        for (int r = 0; r < 4; r++) {
            float sv = fmaf(-2.0f, acc[r], eev);
            if (sv <= thr[r]) {
                const int row = wv * 16 + ((l >> 4) << 2) + r;
                int pos = atomicAdd(&cnt_s[row], 1);
                if (pos < CAP) cand_s[row][pos] = (unsigned short)code;
            }
        }
    }
    __syncthreads();

    // ---- exact rescore (reference-bit-exact chain), one thread per row ----
    if (tid < 64) {
        const int w = tid;
        const float zzv = zz_s[w];
        float bv = INFINITY;
        int bi = 0;
        const int nc = cnt_s[w];
        if (nc > CAP) {
            for (int k = 0; k < KCODES; k++) {
                const float* er = emb + (size_t)k * 64;
                float dot = 0.0f;
#pragma unroll
                for (int d = 0; d < 64; d++)
                    dot = __builtin_fmaf(zt[w][d], er[d], dot);
                float tt = zzv + ee[k];
                float dv = tt - 2.0f * dot;
                if (dv < bv || (dv == bv && k < bi)) { bv = dv; bi = k; }
            }
        } else {
            for (int j = 0; j < nc; j++) {
                const int k = cand_s[w][j];
                const float* er = emb + (size_t)k * 64;
                float dot = 0.0f;
#pragma unroll
                for (int d = 0; d < 64; d++)
                    dot = __builtin_fmaf(zt[w][d], er[d], dot);
                float tt = zzv + ee[k];
                float dv = tt - 2.0f * dot;
                if (dv < bv || (dv == bv && k < bi)) { bv = dv; bi = k; }
            }
        }
        idx_s[w] = bi;
        out_idx[n0 + w] = (float)bi;
        atomicAdd(&counts[bi], 1);
    }
    __syncthreads();

    // ---- fused output: quantized gather/store + fp64 loss ----
    float* qb = out_q + (size_t)b * 262144 + (size_t)h * 64;
    double dsum = 0.0;
    for (int i = tid; i < 4096; i += 256) {
        int c = i >> 6, w = i & 63;
        float q = emb[(size_t)idx_s[w] * 64 + c];
        float zv = zt[w][c];
        qb[(size_t)c * 4096 + w] = q;
        float df = q - zv;
        float s = df * df;
        dsum += (double)s;
    }
    for (int off = 32; off > 0; off >>= 1) dsum += __shfl_down(dsum, off, 64);
    if ((tid & 63) == 0) wred[tid >> 6] = dsum;
    __syncthreads();
    if (tid == 0) {
        double tot = (wred[0] + wred[1]) + (wred[2] + wred[3]);
        atomicAdd(loss_sum, tot);
    }
}

// --- kernel C: loss + perplexity scalars ---
__global__ __launch_bounds__(1024) void kC(const int* __restrict__ counts,
                                           const double* __restrict__ loss_sum,
                                           float* __restrict__ out_loss,
                                           float* __restrict__ out_perp) {
    __shared__ float wr[16];
    const int tid = threadIdx.x;
    float p = (float)counts[tid] * (1.0f / 131072.0f);
    float v = p + 1e-10f;
    float term = p * logf(v);
    float s = term;
    for (int off = 32; off > 0; off >>= 1) s += __shfl_down(s, off, 64);
    if ((tid & 63) == 0) wr[tid >> 6] = s;
    __syncthreads();
    if (tid == 0) {
        float tot = 0.0f;
#pragma unroll
        for (int j = 0; j < 16; j++) tot += wr[j];
        out_perp[0] = expf(-tot);
        double L = *loss_sum / 8388608.0;
        float Lf = (float)L;
        out_loss[0] = Lf + 0.25f * Lf;
    }
}

extern "C" void kernel_launch(void* const* d_in, const int* in_sizes, int n_in,
                              void* d_out, int out_size, void* d_ws, size_t ws_size,
                              hipStream_t stream) {
    const float* z = (const float*)d_in[0];
    const float* emb = (const float*)d_in[1];
    float* out = (float*)d_out;
    float* out_q = out;                    // 8388608
    float* out_loss = out + 8388608;       // 1
    float* out_perp = out + 8388609;       // 1
    float* out_idx = out + 8388610;        // 131072

    char* ws = (char*)d_ws;
    double* loss_sum = (double*)ws;                       // 8 B @ 0
    int* counts = (int*)(ws + 64);                        // 4 KB
    float* ee = (float*)(ws + 64 + 4096);                 // 4 KB
    unsigned short* eh_p = (unsigned short*)(ws + 64 + 8192);  // 128 KB

    hipMemsetAsync(d_ws, 0, 64 + 4096, stream);
    kE<<<4, 256, 0, stream>>>(emb, ee, eh_p);
    kA2<<<2048, 256, 0, stream>>>(z, emb, ee, eh_p, counts, out_idx, out_q,
                                  loss_sum);
    kC<<<1, 1024, 0, stream>>>(counts, loss_sum, out_loss, out_perp);
}

// Round 8
// 158.368 us; speedup vs baseline: 2.2312x; 2.2312x over previous
//
#include <hip/hip_runtime.h>
#include <math.h>

// VQ-VAE vector quantizer for MI355X.
// z: [32, 64, 64, 64] fp32 (B, C=D, H, W), embedding: [1024, 64] fp32.
// Outputs (concatenated fp32 in d_out):
//   [0 .. 8388607]  quantized, layout (b, c, h, w)
//   [8388608]       loss = L + 0.25*L, L = mean((q - z)^2)
//   [8388609]       perplexity
//   [8388610 .. ]   encoding indices (as float), 131072 of them
//
// Round 8: round 7 (MFMA filter + exact rescore) was L2-LATENCY bound:
// 207 cyc/sweep-iteration == L2 hit latency, no load pipelining (MfmaUtil
// 7.8%, VALUBusy 10.8%). Fix: (1) wave->K-split: each wave holds A-frags for
// ALL 64 rows (4 row-tiles) and owns 256 codes -> 16 MFMAs per 32B B-load,
// sweeps 64->16 iters; (2) explicit next-iter B prefetch (named bufs);
// (3) ee staged to LDS. Filter window / exact-rescore math unchanged
// (round 7 passed with exact indices).

#define NROWS 131072
#define KCODES 1024
#define DDIM 64
#define CAP 16

typedef __attribute__((ext_vector_type(8))) short short8v;  // 8 bf16
typedef __attribute__((ext_vector_type(4))) float f32x4;

// Prevent fp contraction (hipcc defaults to -ffp-contract=fast).
__device__ __forceinline__ float nofuse(float x) {
    asm("" : "+v"(x));
    return x;
}

// numpy pairwise_sum for n=64 of terms a[i]*a[i] (8-stripe + fixed tree).
template <typename F>
__device__ __forceinline__ float pairwise64_sq(F load) {
    float r[8];
#pragma unroll
    for (int j = 0; j < 8; j++) {
        float v = load(j);
        r[j] = nofuse(v * v);
    }
#pragma unroll
    for (int i = 8; i < 64; i += 8) {
#pragma unroll
        for (int j = 0; j < 8; j++) {
            float v = load(i + j);
            r[j] = r[j] + nofuse(v * v);
        }
    }
    return ((r[0] + r[1]) + (r[2] + r[3])) + ((r[4] + r[5]) + (r[6] + r[7]));
}

__device__ __forceinline__ unsigned short bf16_rne(float x) {
    unsigned u = __float_as_uint(x);
    u += 0x7FFFu + ((u >> 16) & 1u);
    return (unsigned short)(u >> 16);
}
__device__ __forceinline__ float bf16_tof(unsigned short h) {
    return __uint_as_float((unsigned)h << 16);
}

// --- kernel E: ee[k] (numpy-pairwise exact) + eh bf16 pack ---
__global__ __launch_bounds__(256) void kE(const float* __restrict__ emb,
                                          float* __restrict__ ee,
                                          unsigned short* __restrict__ eh_p) {
    int k = blockIdx.x * 256 + threadIdx.x;
    if (k >= KCODES) return;
    const float* er = emb + (size_t)k * DDIM;
    ee[k] = pairwise64_sq([&](int i) { return er[i]; });
#pragma unroll
    for (int i = 0; i < DDIM; i++) eh_p[(size_t)k * DDIM + i] = bf16_rne(er[i]);
}

#define MFMA_BF16(acc, a, b) \
    acc = __builtin_amdgcn_mfma_f32_16x16x32_bf16(a, b, acc, 0, 0, 0)

// 16 MFMAs (4 row-tiles x K=64) for one 16-code tile, then ACT per score.
// Identical arithmetic in both sweeps -> bit-identical s~ values.
#define DOT_TILE(ti, B0, B1, ACT)                                       \
    {                                                                   \
        const int codeL = code0 + (ti) * 16 + (l & 15);                 \
        const float eev = ee_s[codeL];                                  \
        _Pragma("unroll") for (int rt = 0; rt < 4; rt++) {              \
            f32x4 acc = {0.f, 0.f, 0.f, 0.f};                           \
            MFMA_BF16(acc, ah[rt][0], B0);                              \
            MFMA_BF16(acc, ah[rt][1], B1);                              \
            MFMA_BF16(acc, al[rt][0], B0);                              \
            MFMA_BF16(acc, al[rt][1], B1);                              \
            _Pragma("unroll") for (int r = 0; r < 4; r++) {             \
                float sv = fmaf(-2.0f, acc[r], eev);                    \
                ACT(rt, r, sv, codeL);                                  \
            }                                                           \
        }                                                               \
    }

#define ACT_MIN(rt, r, sv, code) rm[rt][r] = fminf(rm[rt][r], sv);
#define ACT_COLLECT(rt, r, sv, code)                                    \
    if (sv <= thr[rt][r]) {                                             \
        int row_ = rt * 16 + ((l >> 4) << 2) + r;                       \
        int pos_ = atomicAdd(&cnt_s[row_], 1);                          \
        if (pos_ < CAP) cand_s[row_][pos_] = (unsigned short)(code);    \
    }

// --- kernel A2: MFMA filter + exact rescore + fused outputs ---
// Block: 256 threads (4 waves), 64 rows = one (b,h). Wave wv owns codes
// [wv*256, wv*256+256) for ALL 64 rows (A-frags for 4 row-tiles in VGPRs).
// MFMA 16x16x32 bf16: A[m][k]: m=lane&15, k=(lane>>4)*8+i; B[k][n]:
// n=lane&15, same k; D[m][n]: n=lane&15, m=(lane>>4)*4+reg (m89-verified).
__global__ __launch_bounds__(256) void kA2(const float* __restrict__ z,
                                           const float* __restrict__ emb,
                                           const float* __restrict__ ee,
                                           const unsigned short* __restrict__ eh_p,
                                           int* __restrict__ counts,
                                           float* __restrict__ out_idx,
                                           float* __restrict__ out_q,
                                           double* __restrict__ loss_sum) {
    __shared__ float zt[64][65];       // [w][d]
    __shared__ float ee_s[KCODES];     // exact ee bit-copy
    __shared__ float zz_s[64];
    __shared__ float wq_s[64];         // per-row window W_row
    __shared__ float rmw_s[4][64];     // per-wave row mins
    __shared__ int cnt_s[64];
    __shared__ unsigned short cand_s[64][CAP];
    __shared__ int idx_s[64];
    __shared__ double wred[4];

    const int tid = threadIdx.x;
    const int blk = blockIdx.x;        // 0..2047
    const int n0 = blk * 64;
    const int b = blk >> 6;
    const int h = blk & 63;

    // stage z tile (coalesced over w) + ee copy
    const float* zb = z + (size_t)b * 262144 + (size_t)h * 64;
    for (int i = tid; i < 64 * 64; i += 256) {
        int d = i >> 6, w = i & 63;
        zt[w][d] = zb[(size_t)d * 4096 + w];
    }
    for (int i = tid; i < KCODES; i += 256) ee_s[i] = ee[i];
    __syncthreads();

    if (tid < 64) {
        const int w = tid;
        zz_s[w] = pairwise64_sq([&](int i) { return zt[w][i]; });
        float s = 0.0f;
#pragma unroll
        for (int i = 0; i < 64; i++) s += fabsf(zt[w][i]);
        wq_s[w] = fmaf(1e-5f, s, 1e-4f);
        cnt_s[w] = 0;
    }
    __syncthreads();

    const int wv = tid >> 6;           // wave id -> code range
    const int l = tid & 63;            // lane
    const int kg = (l >> 4) * 8;       // k-slice base within 32-wide half
    const int code0 = wv * 256;

    // A fragments for ALL 64 rows (4 row-tiles), zh + zl RNE split
    short8v ah[4][2], al[4][2];
#pragma unroll
    for (int rt = 0; rt < 4; rt++) {
        const int arow = rt * 16 + (l & 15);
#pragma unroll
        for (int kt = 0; kt < 2; kt++) {
#pragma unroll
            for (int i = 0; i < 8; i++) {
                float x = zt[arow][kt * 32 + kg + i];
                unsigned short hh = bf16_rne(x);
                ah[rt][kt][i] = (short)hh;
                al[rt][kt][i] = (short)bf16_rne(x - bf16_tof(hh));
            }
        }
    }

    const unsigned short* ebase = eh_p + (size_t)code0 * 64;

    // ---- sweep 1: per-row approx min over this wave's 256 codes ----
    float rm[4][4];
#pragma unroll
    for (int rt = 0; rt < 4; rt++)
#pragma unroll
        for (int r = 0; r < 4; r++) rm[rt][r] = INFINITY;

    {
        short8v b0A, b1A, b0B, b1B;
        const unsigned short* p0 = ebase + (size_t)(l & 15) * 64 + kg;
        b0A = *(const short8v*)p0;
        b1A = *(const short8v*)(p0 + 32);
#pragma unroll 4
        for (int ti = 0; ti < 16; ti++) {
            if (ti < 15) {
                const unsigned short* p =
                    ebase + (size_t)((ti + 1) * 16 + (l & 15)) * 64 + kg;
                b0B = *(const short8v*)p;
                b1B = *(const short8v*)(p + 32);
            }
            DOT_TILE(ti, b0A, b1A, ACT_MIN)
            if (ti < 15) { b0A = b0B; b1A = b1B; }
        }
    }
    // reduce min across the 16 lanes (codes) in each lane group
#pragma unroll
    for (int rt = 0; rt < 4; rt++)
#pragma unroll
        for (int r = 0; r < 4; r++) {
            float v = rm[rt][r];
            v = fminf(v, __shfl_xor(v, 1, 64));
            v = fminf(v, __shfl_xor(v, 2, 64));
            v = fminf(v, __shfl_xor(v, 4, 64));
            v = fminf(v, __shfl_xor(v, 8, 64));
            rm[rt][r] = v;
        }
    if ((l & 15) == 0) {
#pragma unroll
        for (int rt = 0; rt < 4; rt++)
#pragma unroll
            for (int r = 0; r < 4; r++)
                rmw_s[wv][rt * 16 + ((l >> 4) << 2) + r] = rm[rt][r];
    }
    __syncthreads();

    // per-lane thresholds for its 16 (rt,r) rows: global min + W_row
    float thr[4][4];
#pragma unroll
    for (int rt = 0; rt < 4; rt++)
#pragma unroll
        for (int r = 0; r < 4; r++) {
            const int row = rt * 16 + ((l >> 4) << 2) + r;
            float m01 = fminf(rmw_s[0][row], rmw_s[1][row]);
            float m23 = fminf(rmw_s[2][row], rmw_s[3][row]);
            thr[rt][r] = fminf(m01, m23) + wq_s[row];
        }

    // ---- sweep 2: identical arithmetic, collect window candidates ----
    {
        short8v b0A, b1A, b0B, b1B;
        const unsigned short* p0 = ebase + (size_t)(l & 15) * 64 + kg;
        b0A = *(const short8v*)p0;
        b1A = *(const short8v*)(p0 + 32);
#pragma unroll 4
        for (int ti = 0; ti < 16; ti++) {
            if (ti < 15) {
                const unsigned short* p =
                    ebase + (size_t)((ti + 1) * 16 + (l & 15)) * 64 + kg;
                b0B = *(const short8v*)p;
                b1B = *(const short8v*)(p + 32);
            }
            DOT_TILE(ti, b0A, b1A, ACT_COLLECT)
            if (ti < 15) { b0A = b0B; b1A = b1B; }
        }
    }
    __syncthreads();

    // ---- exact rescore (reference-bit-exact chain), one thread per row ----
    if (tid < 64) {
        const int w = tid;
        const float zzv = zz_s[w];
        float bv = INFINITY;
        int bi = 0;
        const int nc = cnt_s[w];
        if (nc > CAP) {
            for (int k = 0; k < KCODES; k++) {
                const float* er = emb + (size_t)k * 64;
                float dot = 0.0f;
#pragma unroll
                for (int d = 0; d < 64; d++)
                    dot = __builtin_fmaf(zt[w][d], er[d], dot);
                float tt = zzv + ee_s[k];
                float dv = tt - 2.0f * dot;
                if (dv < bv || (dv == bv && k < bi)) { bv = dv; bi = k; }
            }
        } else {
            for (int j = 0; j < nc; j++) {
                const int k = cand_s[w][j];
                const float* er = emb + (size_t)k * 64;
                float dot = 0.0f;
#pragma unroll
                for (int d = 0; d < 64; d++)
                    dot = __builtin_fmaf(zt[w][d], er[d], dot);
                float tt = zzv + ee_s[k];
                float dv = tt - 2.0f * dot;
                if (dv < bv || (dv == bv && k < bi)) { bv = dv; bi = k; }
            }
        }
        idx_s[w] = bi;
        out_idx[n0 + w] = (float)bi;
        atomicAdd(&counts[bi], 1);
    }
    __syncthreads();

    // ---- fused output: quantized gather/store + fp64 loss ----
    float* qb = out_q + (size_t)b * 262144 + (size_t)h * 64;
    double dsum = 0.0;
    for (int i = tid; i < 4096; i += 256) {
        int c = i >> 6, w = i & 63;
        float q = emb[(size_t)idx_s[w] * 64 + c];
        float zv = zt[w][c];
        qb[(size_t)c * 4096 + w] = q;
        float df = q - zv;
        float s = df * df;
        dsum += (double)s;
    }
    for (int off = 32; off > 0; off >>= 1) dsum += __shfl_down(dsum, off, 64);
    if ((tid & 63) == 0) wred[tid >> 6] = dsum;
    __syncthreads();
    if (tid == 0) {
        double tot = (wred[0] + wred[1]) + (wred[2] + wred[3]);
        atomicAdd(loss_sum, tot);
    }
}

// --- kernel C: loss + perplexity scalars ---
__global__ __launch_bounds__(1024) void kC(const int* __restrict__ counts,
                                           const double* __restrict__ loss_sum,
                                           float* __restrict__ out_loss,
                                           float* __restrict__ out_perp) {
    __shared__ float wr[16];
    const int tid = threadIdx.x;
    float p = (float)counts[tid] * (1.0f / 131072.0f);
    float v = p + 1e-10f;
    float term = p * logf(v);
    float s = term;
    for (int off = 32; off > 0; off >>= 1) s += __shfl_down(s, off, 64);
    if ((tid & 63) == 0) wr[tid >> 6] = s;
    __syncthreads();
    if (tid == 0) {
        float tot = 0.0f;
#pragma unroll
        for (int j = 0; j < 16; j++) tot += wr[j];
        out_perp[0] = expf(-tot);
        double L = *loss_sum / 8388608.0;
        float Lf = (float)L;
        out_loss[0] = Lf + 0.25f * Lf;
    }
}

extern "C" void kernel_launch(void* const* d_in, const int* in_sizes, int n_in,
                              void* d_out, int out_size, void* d_ws, size_t ws_size,
                              hipStream_t stream) {
    const float* z = (const float*)d_in[0];
    const float* emb = (const float*)d_in[1];
    float* out = (float*)d_out;
    float* out_q = out;                    // 8388608
    float* out_loss = out + 8388608;       // 1
    float* out_perp = out + 8388609;       // 1
    float* out_idx = out + 8388610;        // 131072

    char* ws = (char*)d_ws;
    double* loss_sum = (double*)ws;                       // 8 B @ 0
    int* counts = (int*)(ws + 64);                        // 4 KB
    float* ee = (float*)(ws + 64 + 4096);                 // 4 KB
    unsigned short* eh_p = (unsigned short*)(ws + 64 + 8192);  // 128 KB

    hipMemsetAsync(d_ws, 0, 64 + 4096, stream);
    kE<<<4, 256, 0, stream>>>(emb, ee, eh_p);
    kA2<<<2048, 256, 0, stream>>>(z, emb, ee, eh_p, counts, out_idx, out_q,
                                  loss_sum);
    kC<<<1, 1024, 0, stream>>>(counts, loss_sum, out_loss, out_perp);
}